// Round 3
// baseline (386.976 us; speedup 1.0000x reference)
//
#include <hip/hip_runtime.h>

#define BLKE 524288      // 128*64*64
#define VOLE 4194304     // 256*128*128
#define TCROP 2097152    // 128*128*128 (t<128 compact complex volume)
#define PI2 6.283185307179586476925286766559

__device__ __forceinline__ float2 cmulf(float2 a, float2 b){
  return make_float2(a.x*b.x - a.y*b.y, a.x*b.y + a.y*b.x);
}
__device__ __forceinline__ float waveSum(float v){
  #pragma unroll
  for (int o=32;o;o>>=1) v += __shfl_xor(v,o);
  return v;
}
__device__ __forceinline__ float waveMaxf(float v){
  #pragma unroll
  for (int o=32;o;o>>=1) v = fmaxf(v,__shfl_xor(v,o));
  return v;
}
__device__ __forceinline__ float waveMinf(float v){
  #pragma unroll
  for (int o=32;o;o>>=1) v = fminf(v,__shfl_xor(v,o));
  return v;
}

// Reduce pA[kappa][256][5] redundantly in every block (identical FP order ->
// identical result in all blocks). Requires blockDim.x == 256.
__device__ __forceinline__ void bcastReduce5(const float* __restrict__ pA, int kap,
    float& sum, float& mnl, float& mxl, float& mnh, float& mxh, float* sm /*>=20*/){
  int tid = threadIdx.x;
  const float* q = pA + kap*1280 + tid*5;
  float s = q[0], a = q[1], b = q[2], c = q[3], d = q[4];
  s = waveSum(s); a = waveMinf(a); b = waveMaxf(b); c = waveMinf(c); d = waveMaxf(d);
  if ((tid&63)==0){ int w = tid>>6; sm[w]=s; sm[4+w]=a; sm[8+w]=b; sm[12+w]=c; sm[16+w]=d; }
  __syncthreads();
  sum = sm[0]+sm[1]+sm[2]+sm[3];
  mnl = fminf(fminf(sm[4],sm[5]),fminf(sm[6],sm[7]));
  mxl = fmaxf(fmaxf(sm[8],sm[9]),fmaxf(sm[10],sm[11]));
  mnh = fminf(fminf(sm[12],sm[13]),fminf(sm[14],sm[15]));
  mxh = fmaxf(fmaxf(sm[16],sm[17]),fmaxf(sm[18],sm[19]));
}

__device__ __forceinline__ float bcastSum256(const float* __restrict__ p, float* sm /*>=4*/){
  int tid = threadIdx.x;
  float s = waveSum(p[tid]);
  if ((tid&63)==0) sm[tid>>6] = s;
  __syncthreads();
  return sm[0]+sm[1]+sm[2]+sm[3];
}

// ---------------- fused conv+mtx operator: M[o][t][s] ----------------
__global__ void kM(const float* __restrict__ mtx, const float* __restrict__ wave,
                   float* __restrict__ M){
  int idx = blockIdx.x*256 + threadIdx.x;   // 32768 = 2*128*128
  int o = idx >> 14, r = idx & 16383;
  int t = r >> 7, s = r & 127;
  float acc = 0.f;
  int mlo = s-31; if (mlo < 0) mlo = 0;
  int mhi = s+31; if (mhi > 127) mhi = 127;
  for (int m = mlo; m <= mhi; m++) acc += mtx[t*128+m]*wave[o*63 + (s-m+31)];
  M[idx] = acc;
}

// ---------------- tmp[o*2+b][t][x] = sum_s M[o][t][s]*feature[b][s][x] ----------------
__global__ void __launch_bounds__(256) kTmp(const float* __restrict__ feat,
                                            const float* __restrict__ M,
                                            float* __restrict__ tmp){
  __shared__ float LF[32][64];
  __shared__ float LM[2][32][33];
  int b = blockIdx.z, tt = blockIdx.y, xt = blockIdx.x;
  int tid = threadIdx.x;
  int xx = tid & 63, tq = tid >> 6;
  float acc0[8] = {}, acc1[8] = {};
  const float* fb = feat + (size_t)b*BLKE;
  for (int sb = 0; sb < 4; sb++){
    #pragma unroll
    for (int j = 0; j < 8; j++){
      int idx = tid + j*256; int s = idx >> 6, x = idx & 63;
      LF[s][x] = fb[(size_t)(sb*32+s)*4096 + xt*64 + x];
    }
    #pragma unroll
    for (int j = 0; j < 8; j++){
      int idx = tid + j*256; int o = idx >> 10, r = idx & 1023;
      int trow = r >> 5, s = r & 31;
      LM[o][trow][s] = M[o*16384 + (tt*32+trow)*128 + sb*32+s];
    }
    __syncthreads();
    for (int s = 0; s < 32; s++){
      float f = LF[s][xx];
      #pragma unroll
      for (int i = 0; i < 8; i++){
        acc0[i] += LM[0][tq*8+i][s]*f;
        acc1[i] += LM[1][tq*8+i][s]*f;
      }
    }
    __syncthreads();
  }
  #pragma unroll
  for (int i = 0; i < 8; i++){
    int t = tt*32 + tq*8 + i;
    tmp[(size_t)(0*2+b)*BLKE + (size_t)t*4096 + xt*64+xx] = acc0[i];
    tmp[(size_t)(1*2+b)*BLKE + (size_t)t*4096 + xt*64+xx] = acc1[i];
  }
}

// ---------------- attention reductions (atomic-free, partials in ws) -------
__global__ void __launch_bounds__(256) kRedA(const float* __restrict__ Kr,
                                             const float* __restrict__ Ki,
                                             float* __restrict__ Lw, float* __restrict__ Hw,
                                             float* __restrict__ pA){
  const float* K = blockIdx.y ? Ki : Kr;
  int kap = blockIdx.y;
  __shared__ float spe[128];
  __shared__ float sm[20];
  int tid = threadIdx.x;
  if (tid < 128) spe[tid] = sinf((float)tid);
  __syncthreads();
  float sum=0.f, mnl=3.4e38f, mxl=-3.4e38f, mnh=3.4e38f, mxh=-3.4e38f;
  int base = blockIdx.x*256 + tid;
  #pragma unroll
  for (int it = 0; it < 8; it++){
    int e = base + it*65536;
    int tau = e >> 12, rem = e & 4095, eta = rem >> 6, om = rem & 63;
    float pe = spe[tau];
    float lo = K[(size_t)((tau+192)&255)*16384 + ((eta+96)&127)*128 + ((om+96)&127)];
    float hi = K[(size_t)(tau+64)*16384 + (eta+32)*128 + (om+32)];
    sum += lo;
    float lp = lo+pe, hp = hi+pe;
    Lw[kap*BLKE + e] = lp;
    Hw[kap*BLKE + e] = hp;
    mnl=fminf(mnl,lp); mxl=fmaxf(mxl,lp);
    mnh=fminf(mnh,hp); mxh=fmaxf(mxh,hp);
  }
  sum = waveSum(sum); mnl=waveMinf(mnl); mxl=waveMaxf(mxl); mnh=waveMinf(mnh); mxh=waveMaxf(mxh);
  if ((tid&63)==0){ int w=tid>>6; sm[w]=sum; sm[4+w]=mnl; sm[8+w]=mxl; sm[12+w]=mnh; sm[16+w]=mxh; }
  __syncthreads();
  if (tid==0){
    float* o = pA + kap*1280 + blockIdx.x*5;
    o[0] = sm[0]+sm[1]+sm[2]+sm[3];
    o[1] = fminf(fminf(sm[4],sm[5]),fminf(sm[6],sm[7]));
    o[2] = fmaxf(fmaxf(sm[8],sm[9]),fmaxf(sm[10],sm[11]));
    o[3] = fminf(fminf(sm[12],sm[13]),fminf(sm[14],sm[15]));
    o[4] = fmaxf(fmaxf(sm[16],sm[17]),fmaxf(sm[18],sm[19]));
  }
}

__global__ void __launch_bounds__(256) kRedB(const float* __restrict__ pA,
                                             const float* __restrict__ Lw,
                                             float* __restrict__ pB,
                                             const float* cw, const float* cb){
  int kap = blockIdx.y;
  __shared__ float sm[20], smo[4];
  float sum,mnl,mxl,mnh,mxh;
  bcastReduce5(pA,kap,sum,mnl,mxl,mnh,mxh,sm);
  float w = cw[0], b = cb[0];
  float s1 = w*(sum*(1.0f/BLKE)) + b;
  float a1 = s1*w, c1 = s1*b;
  float mx = (a1>=0.f) ? a1*mxl+c1 : a1*mnl+c1;
  float acc = 0.f;
  int base = kap*BLKE + blockIdx.x*256 + threadIdx.x;
  #pragma unroll
  for (int it = 0; it < 8; it++){
    float lp = Lw[base + it*65536];
    acc += expf(a1*lp + c1 - mx);
  }
  acc = waveSum(acc);
  if ((threadIdx.x&63)==0) smo[threadIdx.x>>6] = acc;
  __syncthreads();
  if (threadIdx.x==0) pB[kap*256 + blockIdx.x] = smo[0]+smo[1]+smo[2]+smo[3];
}

__global__ void __launch_bounds__(256) kRedC(const float* __restrict__ pA,
                                             const float* __restrict__ pB,
                                             const float* __restrict__ Lw,
                                             float* __restrict__ pC,
                                             const float* cw, const float* cb){
  int kap = blockIdx.y;
  __shared__ float sm[20], smB[4], smo[4];
  float sum,mnl,mxl,mnh,mxh;
  bcastReduce5(pA,kap,sum,mnl,mxl,mnh,mxh,sm);
  float d1 = bcastSum256(pB + kap*256, smB);
  float w = cw[0], b = cb[0];
  float s1 = w*(sum*(1.0f/BLKE)) + b;
  float a1 = s1*w, c1 = s1*b;
  float mx = (a1>=0.f) ? a1*mxl+c1 : a1*mnl+c1;
  float invd = 1.0f/d1;
  float acc = 0.f;
  int base = kap*BLKE + blockIdx.x*256 + threadIdx.x;
  #pragma unroll
  for (int it = 0; it < 8; it++){
    float lp = Lw[base + it*65536];
    float p = expf(a1*lp + c1 - mx)*invd;
    acc += lp/(1.f + expf(-p));
  }
  acc = waveSum(acc);
  if ((threadIdx.x&63)==0) smo[threadIdx.x>>6] = acc;
  __syncthreads();
  if (threadIdx.x==0) pC[kap*256 + blockIdx.x] = smo[0]+smo[1]+smo[2]+smo[3];
}

__global__ void __launch_bounds__(256) kRedD(const float* __restrict__ pA,
                                             const float* __restrict__ pC,
                                             const float* __restrict__ Hw,
                                             float* __restrict__ pD,
                                             const float* cw, const float* cb){
  int kap = blockIdx.y;
  __shared__ float sm[20], smC[4], smo[4];
  float sum,mnl,mxl,mnh,mxh;
  bcastReduce5(pA,kap,sum,mnl,mxl,mnh,mxh,sm);
  float sl2 = bcastSum256(pC + kap*256, smC);
  float w = cw[0], b = cb[0];
  float s2 = w*(sl2*(1.0f/BLKE)) + b;
  float a2 = s2*w, c2 = s2*b;
  float mx = (a2>=0.f) ? a2*mxh+c2 : a2*mnh+c2;
  float acc = 0.f;
  int base = kap*BLKE + blockIdx.x*256 + threadIdx.x;
  #pragma unroll
  for (int it = 0; it < 8; it++){
    float hp = Hw[base + it*65536];
    acc += expf(a2*hp + c2 - mx);
  }
  acc = waveSum(acc);
  if ((threadIdx.x&63)==0) smo[threadIdx.x>>6] = acc;
  __syncthreads();
  if (threadIdx.x==0) pD[kap*256 + blockIdx.x] = smo[0]+smo[1]+smo[2]+smo[3];
}

// finalize: scal[kap*8 + {0..7}] = {a1,c1,mx1,1/d1, a2,c2,mx2,1/d2}
__global__ void __launch_bounds__(256) kFin(const float* __restrict__ pA,
                                            const float* __restrict__ pB,
                                            const float* __restrict__ pC,
                                            const float* __restrict__ pD,
                                            float* __restrict__ scal,
                                            const float* cw, const float* cb){
  __shared__ float sm[20], smB[4], smC[4], smD[4];
  for (int kap = 0; kap < 2; kap++){
    if (kap) __syncthreads();
    float sum,mnl,mxl,mnh,mxh;
    bcastReduce5(pA,kap,sum,mnl,mxl,mnh,mxh,sm);
    float d1  = bcastSum256(pB + kap*256, smB);
    float sl2 = bcastSum256(pC + kap*256, smC);
    float d2  = bcastSum256(pD + kap*256, smD);
    if (threadIdx.x==0){
      float w = cw[0], b = cb[0];
      float s1 = w*(sum*(1.0f/BLKE)) + b;
      float a1 = s1*w, c1 = s1*b;
      float mx1 = (a1>=0.f) ? a1*mxl+c1 : a1*mnl+c1;
      float s2 = w*(sl2*(1.0f/BLKE)) + b;
      float a2 = s2*w, c2 = s2*b;
      float mx2 = (a2>=0.f) ? a2*mxh+c2 : a2*mnh+c2;
      float* Q = scal + kap*8;
      Q[0]=a1; Q[1]=c1; Q[2]=mx1; Q[3]=1.0f/d1;
      Q[4]=a2; Q[5]=c2; Q[6]=mx2; Q[7]=1.0f/d2;
    }
  }
}

// ---------------- W-axis forward FFT, packed load from tmp; grid.y = b ------
__global__ void __launch_bounds__(256) kF1(const float* __restrict__ tmp,
                                           float2* __restrict__ Z2){
  __shared__ float2 bA[4][130], bB[4][130], tw[64];
  int tid = threadIdx.x;
  if (tid < 64){
    double ang = -PI2 * (double)tid / 128.0;
    tw[tid] = make_float2((float)cos(ang), (float)sin(ang));
  }
  int b = blockIdx.y;
  int l = tid >> 6, lane = tid & 63;
  int line = blockIdx.x*4 + l;
  int t = line >> 6, h = line & 63;
  const float* pc = tmp + (size_t)b*BLKE + (size_t)t*4096 + h*64;
  const float* ps = tmp + (size_t)(2+b)*BLKE + (size_t)t*4096 + h*64;
  bA[l][lane] = make_float2(pc[lane], ps[lane]);
  bA[l][lane+64] = make_float2(0.f, 0.f);
  __syncthreads();
  float2 (*src)[130] = bA, (*dst)[130] = bB;
  int m = 1;
  #pragma unroll
  for (int st = 0; st < 7; st++){
    int i = lane;
    int jm = i & ~(m-1);
    float2 a = src[l][i], b2 = src[l][i+64];
    float2 s = make_float2(a.x+b2.x, a.y+b2.y);
    float2 d = make_float2(a.x-b2.x, a.y-b2.y);
    dst[l][i+jm]   = s;
    dst[l][i+jm+m] = cmulf(d, tw[jm]);
    __syncthreads();
    float2 (*tp)[130] = src; src = dst; dst = tp;
    m <<= 1;
  }
  float2* outp = Z2 + (size_t)b*VOLE + (size_t)t*16384 + (size_t)h*128;
  outp[lane]    = src[l][lane];
  outp[lane+64] = src[l][lane+64];
}

// ---------------- H-axis forward (N=128): read h<64, write all; grid.y=b ----
__global__ void __launch_bounds__(256) kHf(float2* __restrict__ Z2){
  __shared__ float2 bA[16][130], bB[16][130], tw[64];
  int tid = threadIdx.x;
  if (tid < 64){
    double ang = -PI2 * (double)tid / 128.0;
    tw[tid] = make_float2((float)cos(ang), (float)sin(ang));
  }
  float2* Z = Z2 + (size_t)blockIdx.y*VOLE;
  int bid = blockIdx.x;                 // 1024 : t<128 x 8 w-groups
  int t = bid >> 3; int w0 = (bid & 7) << 4;
  size_t base = (size_t)t*16384 + w0;
  #pragma unroll
  for (int q = 0; q < 4; q++){
    int idx = q*256 + tid; int wl = idx & 15, hh = idx >> 4;
    bA[wl][hh] = Z[base + (size_t)hh*128 + wl];
    bA[wl][hh+64] = make_float2(0.f, 0.f);
  }
  __syncthreads();
  float2 (*src)[130] = bA, (*dst)[130] = bB;
  int m = 1;
  #pragma unroll
  for (int st = 0; st < 7; st++){
    #pragma unroll
    for (int q = 0; q < 4; q++){
      int g = q*256 + tid; int li = g >> 6; int i = g & 63;
      int jm = i & ~(m-1);
      float2 a = src[li][i], b2 = src[li][i+64];
      float2 s = make_float2(a.x+b2.x, a.y+b2.y);
      float2 d = make_float2(a.x-b2.x, a.y-b2.y);
      dst[li][i+jm]   = s;
      dst[li][i+jm+m] = cmulf(d, tw[jm]);
    }
    __syncthreads();
    float2 (*tp)[130] = src; src = dst; dst = tp;
    m <<= 1;
  }
  #pragma unroll
  for (int q = 0; q < 8; q++){
    int idx = q*256 + tid; int wl = idx & 15, hh = idx >> 4;
    Z[base + (size_t)hh*128 + wl] = src[wl][hh];
  }
}

// ---------------- T-axis forward (N=256): read t<128, write all; grid.y=b ---
__global__ void __launch_bounds__(256) kTf(float2* __restrict__ Z2){
  __shared__ float2 bA[8][258], bB[8][258], tw[128];
  int tid = threadIdx.x;
  if (tid < 128){
    double ang = -PI2 * (double)tid / 256.0;
    tw[tid] = make_float2((float)cos(ang), (float)sin(ang));
  }
  float2* Z = Z2 + (size_t)blockIdx.y*VOLE;
  int bid = blockIdx.x;                 // 2048 : 128 h x 16 w-groups
  int hh = bid >> 4; int w0 = (bid & 15) << 3;
  size_t base = (size_t)hh*128 + w0;
  #pragma unroll
  for (int q = 0; q < 4; q++){
    int idx = q*256 + tid; int wl = idx & 7, t = idx >> 3;
    bA[wl][t] = Z[(size_t)t*16384 + base + wl];
    bA[wl][t+128] = make_float2(0.f, 0.f);
  }
  __syncthreads();
  float2 (*src)[258] = bA, (*dst)[258] = bB;
  int m = 1;
  #pragma unroll
  for (int st = 0; st < 8; st++){
    #pragma unroll
    for (int q = 0; q < 4; q++){
      int g = q*256 + tid; int li = g >> 7; int i = g & 127;
      int jm = i & ~(m-1);
      float2 a = src[li][i], b2 = src[li][i+128];
      float2 s = make_float2(a.x+b2.x, a.y+b2.y);
      float2 d = make_float2(a.x-b2.x, a.y-b2.y);
      dst[li][i+jm]   = s;
      dst[li][i+jm+m] = cmulf(d, tw[jm]);
    }
    __syncthreads();
    float2 (*tp)[258] = src; src = dst; dst = tp;
    m <<= 1;
  }
  #pragma unroll
  for (int q = 0; q < 8; q++){
    int idx = q*256 + tid; int wl = idx & 7, t = idx >> 3;
    Z[(size_t)t*16384 + base + wl] = src[wl][t];
  }
}

// ---------------- inline attention-modified multiplier ----------------
__device__ __forceinline__ float attnv(float v, float a, float c, float mx, float invd){
  float p = expf(a*v + c - mx)*invd;
  return v / (1.f + expf(-p));
}
__device__ __forceinline__ float2 wcAt(int t, int h, int w,
                                       const float* __restrict__ Kr, const float* __restrict__ Ki,
                                       const float* spe, const float* P){
  size_t off = (size_t)t*16384 + (size_t)h*128 + w;
  float kr = Kr[off], ki = Ki[off];
  bool center = (t>=64 && t<192) && (h>=32 && h<96) && (w>=32 && w<96);
  int tc = (t+64)&255, hc = (h+32)&127, wc = (w+32)&127;
  bool corner = (tc<128) && (hc<64) && (wc<64);
  float2 o;
  if (center){
    float pe = spe[t-64];
    o.x = attnv(kr+pe, P[4],  P[5],  P[6],  P[7]);
    o.y = attnv(ki+pe, P[12], P[13], P[14], P[15]);
  } else if (corner){
    float pe = spe[tc];
    o.x = attnv(kr+pe, P[0], P[1],  P[2],  P[3]);
    o.y = attnv(ki+pe, P[8], P[9],  P[10], P[11]);
  } else {
    o.x = kr; o.y = ki;
  }
  return o;
}

// ---- fused multiply + inverse-T (N=256): read all t of Z, write t<128 ------
// grid: (2048, b, uv). uv=0: U(k)=Z(k)*Wc(k). uv=1: V'(k)=Z(k)*conj(Wc(-k)),
// using ifft(conj(Z(-k))Wc(k)) = conj(ifft(Z*conj(Wc(-.)))); final conj in kI3C.
__global__ void __launch_bounds__(256) kTinvMul(const float2* __restrict__ Z2,
                                                float2* __restrict__ U2,
                                                float2* __restrict__ V2,
                                                const float* __restrict__ Kr,
                                                const float* __restrict__ Ki,
                                                const float* __restrict__ scal){
  __shared__ float2 bA[8][258], bB[8][258], tw[128];
  __shared__ float spe[128];
  __shared__ float P[16];
  int tid = threadIdx.x;
  if (tid < 128){
    double ang = PI2 * (double)tid / 256.0;
    tw[tid] = make_float2((float)cos(ang), (float)sin(ang));
    spe[tid] = sinf((float)tid);
  }
  if (tid < 16) P[tid] = scal[tid];
  __syncthreads();
  int b = blockIdx.y, uv = blockIdx.z;
  const float2* Z = Z2 + (size_t)b*VOLE;
  float2* Out = (uv ? V2 : U2) + (size_t)b*TCROP;
  int bid = blockIdx.x;                 // 2048 : 128 h x 16 w-groups
  int hh = bid >> 4; int w0 = (bid & 15) << 3;
  size_t base = (size_t)hh*128 + w0;
  #pragma unroll
  for (int q = 0; q < 8; q++){
    int idx = q*256 + tid; int wl = idx & 7, t = idx >> 3;
    int w_ = w0 + wl;
    float2 z = Z[(size_t)t*16384 + base + wl];
    float2 wc;
    if (uv == 0){
      wc = wcAt(t, hh, w_, Kr, Ki, spe, P);
    } else {
      int tm = (256-t)&255, hm = (128-hh)&127, wm = (128-w_)&127;
      wc = wcAt(tm, hm, wm, Kr, Ki, spe, P);
      wc.y = -wc.y;
    }
    bA[wl][t] = cmulf(z, wc);
  }
  __syncthreads();
  float2 (*src)[258] = bA, (*dst)[258] = bB;
  int m = 1;
  #pragma unroll
  for (int st = 0; st < 8; st++){
    #pragma unroll
    for (int q = 0; q < 4; q++){
      int g = q*256 + tid; int li = g >> 7; int i = g & 127;
      int jm = i & ~(m-1);
      float2 a = src[li][i], b2 = src[li][i+128];
      float2 s = make_float2(a.x+b2.x, a.y+b2.y);
      float2 d = make_float2(a.x-b2.x, a.y-b2.y);
      dst[li][i+jm]   = s;
      dst[li][i+jm+m] = cmulf(d, tw[jm]);
    }
    __syncthreads();
    float2 (*tp)[258] = src; src = dst; dst = tp;
    m <<= 1;
  }
  #pragma unroll
  for (int q = 0; q < 4; q++){
    int idx = q*256 + tid; int wl = idx & 7, t = idx >> 3;   // t < 128
    Out[(size_t)t*16384 + base + wl] = src[wl][t];
  }
}

// ---------------- H-axis inverse (N=128) on compact buffers: grid (1024,b,uv)
__global__ void __launch_bounds__(256) kHi(float2* __restrict__ U2, float2* __restrict__ V2){
  __shared__ float2 bA[16][130], bB[16][130], tw[64];
  int tid = threadIdx.x;
  if (tid < 64){
    double ang = PI2 * (double)tid / 128.0;
    tw[tid] = make_float2((float)cos(ang), (float)sin(ang));
  }
  float2* Z = (blockIdx.z ? V2 : U2) + (size_t)blockIdx.y*TCROP;
  int bid = blockIdx.x;                 // 1024 : t<128 x 8 w-groups
  int t = bid >> 3; int w0 = (bid & 7) << 4;
  size_t base = (size_t)t*16384 + w0;
  #pragma unroll
  for (int q = 0; q < 8; q++){
    int idx = q*256 + tid; int wl = idx & 15, hh = idx >> 4;
    bA[wl][hh] = Z[base + (size_t)hh*128 + wl];
  }
  __syncthreads();
  float2 (*src)[130] = bA, (*dst)[130] = bB;
  int m = 1;
  #pragma unroll
  for (int st = 0; st < 7; st++){
    #pragma unroll
    for (int q = 0; q < 4; q++){
      int g = q*256 + tid; int li = g >> 6; int i = g & 63;
      int jm = i & ~(m-1);
      float2 a = src[li][i], b2 = src[li][i+64];
      float2 s = make_float2(a.x+b2.x, a.y+b2.y);
      float2 d = make_float2(a.x-b2.x, a.y-b2.y);
      dst[li][i+jm]   = s;
      dst[li][i+jm+m] = cmulf(d, tw[jm]);
    }
    __syncthreads();
    float2 (*tp)[130] = src; src = dst; dst = tp;
    m <<= 1;
  }
  #pragma unroll
  for (int q = 0; q < 4; q++){
    int idx = q*256 + tid; int wl = idx & 15, hh = idx >> 4;   // hh < 64
    Z[base + (size_t)hh*128 + wl] = src[wl][hh];
  }
}

// -- fused W-axis inverse + combine: per line FFT U then V; s=y*conj(v)*sc^2 --
__global__ void __launch_bounds__(256) kI3C(const float2* __restrict__ U2,
                                            const float2* __restrict__ V2,
                                            float* __restrict__ sq){
  __shared__ float2 bA[4][130], bB[4][130], tw[64];
  int tid = threadIdx.x;
  if (tid < 64){
    double ang = PI2 * (double)tid / 128.0;
    tw[tid] = make_float2((float)cos(ang), (float)sin(ang));
  }
  int b = blockIdx.y;
  int l = tid >> 6, lane = tid & 63;
  int line = blockIdx.x*4 + l;         // t<128, h<64
  int t = line >> 6, h = line & 63;
  size_t off = (size_t)b*TCROP + (size_t)t*16384 + (size_t)h*128;
  // ---- U line ----
  bA[l][lane]    = U2[off + lane];
  bA[l][lane+64] = U2[off + lane + 64];
  __syncthreads();
  float2 (*src)[130] = bA, (*dst)[130] = bB;
  int m = 1;
  #pragma unroll
  for (int st = 0; st < 7; st++){
    int i = lane;
    int jm = i & ~(m-1);
    float2 a = src[l][i], b2 = src[l][i+64];
    float2 s = make_float2(a.x+b2.x, a.y+b2.y);
    float2 d = make_float2(a.x-b2.x, a.y-b2.y);
    dst[l][i+jm]   = s;
    dst[l][i+jm+m] = cmulf(d, tw[jm]);
    __syncthreads();
    float2 (*tp)[130] = src; src = dst; dst = tp;
    m <<= 1;
  }
  float2 y = src[l][lane];
  // ---- V line (dst != src holds y's buffer; loads go to dst side) ----
  dst[l][lane]    = V2[off + lane];
  dst[l][lane+64] = V2[off + lane + 64];
  __syncthreads();
  src = dst; dst = (src == bA) ? bB : bA;
  m = 1;
  #pragma unroll
  for (int st = 0; st < 7; st++){
    int i = lane;
    int jm = i & ~(m-1);
    float2 a = src[l][i], b2 = src[l][i+64];
    float2 s = make_float2(a.x+b2.x, a.y+b2.y);
    float2 d = make_float2(a.x-b2.x, a.y-b2.y);
    dst[l][i+jm]   = s;
    dst[l][i+jm+m] = cmulf(d, tw[jm]);
    __syncthreads();
    float2 (*tp)[130] = src; src = dst; dst = tp;
    m <<= 1;
  }
  float2 v = src[l][lane];
  // s = y * conj(v) * sc^2  (y' = conj(ifft(Z*conj(Wc(-.)))))
  const float sc = 1.0f/(float)VOLE;
  const float sc2 = sc*sc;
  float2 s = cmulf(y, make_float2(v.x, -v.y));
  s.x *= sc2; s.y *= sc2;
  float mag = 0.5f*(sqrtf(s.x*s.x + s.y*s.y) + s.x);
  mag = fmaxf(mag, 0.f);
  sq[(size_t)b*BLKE + (size_t)t*4096 + h*64 + lane] = sqrtf(mag);
}

// ---------------- out[b][t][x] = sum_m mtxi[t][m]*sq[b][m][x] ----------------
__global__ void __launch_bounds__(256) kOut(const float* __restrict__ sq,
                                            const float* __restrict__ mtxi,
                                            float* __restrict__ out){
  __shared__ float LF[32][64];
  __shared__ float LM[32][33];
  int b = blockIdx.z, tt = blockIdx.y, xt = blockIdx.x;
  int tid = threadIdx.x;
  int xx = tid & 63, tq = tid >> 6;
  float acc[8] = {};
  const float* fb = sq + (size_t)b*BLKE;
  for (int sb = 0; sb < 4; sb++){
    #pragma unroll
    for (int j = 0; j < 8; j++){
      int idx = tid + j*256; int s = idx >> 6, x = idx & 63;
      LF[s][x] = fb[(size_t)(sb*32+s)*4096 + xt*64 + x];
    }
    #pragma unroll
    for (int j = 0; j < 4; j++){
      int idx = tid + j*256; int trow = idx >> 5, s = idx & 31;
      LM[trow][s] = mtxi[(tt*32+trow)*128 + sb*32+s];
    }
    __syncthreads();
    for (int s = 0; s < 32; s++){
      float f = LF[s][xx];
      #pragma unroll
      for (int i = 0; i < 8; i++) acc[i] += LM[tq*8+i][s]*f;
    }
    __syncthreads();
  }
  #pragma unroll
  for (int i = 0; i < 8; i++){
    int t = tt*32 + tq*8 + i;
    out[(size_t)b*BLKE + (size_t)t*4096 + xt*64+xx] = acc[i];
  }
}

extern "C" void kernel_launch(void* const* d_in, const int* in_sizes, int n_in,
                              void* d_out, int out_size, void* d_ws, size_t ws_size,
                              hipStream_t stream){
  const float* feature = (const float*)d_in[0];
  const float* convW   = (const float*)d_in[1];
  const float* convB   = (const float*)d_in[2];
  const float* wave    = (const float*)d_in[3];
  const float* Kr      = (const float*)d_in[4];
  const float* Ki      = (const float*)d_in[5];
  const float* mtx     = (const float*)d_in[6];
  const float* mtxi    = (const float*)d_in[7];
  float* out = (float*)d_out;
  float* ws  = (float*)d_ws;

  float*  M    = ws;                         // 32768
  float*  scal = ws + 32768;                 // 16
  float*  pA   = ws + 32832;                 // 2560
  float*  pB   = ws + 35392;                 // 512
  float*  pC   = ws + 35904;                 // 512
  float*  pD   = ws + 36416;                 // 512
  float*  tmp  = ws + 65536;                 // 2097152
  float*  sq   = ws + 65536 + 2097152;       // 1048576
  float2* Z2   = (float2*)(ws + 3211264);    // 2 * VOLE float2   (67 MB)
  float2* U2   = (float2*)(ws + 19988480);   // 2 * TCROP float2  (33.5 MB)
  float2* V2   = (float2*)(ws + 28377088);   // 2 * TCROP float2  (33.5 MB)
  // Lw/Hw alias U2 (consumed by kRedB/C/D before kTinvMul writes U2)
  float*  Lw   = (float*)U2;                 // 2*BLKE
  float*  Hw   = ((float*)U2) + 1048576;     // 2*BLKE

  kM<<<128, 256, 0, stream>>>(mtx, wave, M);
  kTmp<<<dim3(64,4,2), 256, 0, stream>>>(feature, M, tmp);
  kRedA<<<dim3(256,2), 256, 0, stream>>>(Kr, Ki, Lw, Hw, pA);
  kRedB<<<dim3(256,2), 256, 0, stream>>>(pA, Lw, pB, convW, convB);
  kRedC<<<dim3(256,2), 256, 0, stream>>>(pA, pB, Lw, pC, convW, convB);
  kRedD<<<dim3(256,2), 256, 0, stream>>>(pA, pC, Hw, pD, convW, convB);
  kFin<<<1, 256, 0, stream>>>(pA, pB, pC, pD, scal, convW, convB);

  kF1<<<dim3(2048,2), 256, 0, stream>>>(tmp, Z2);
  kHf<<<dim3(1024,2), 256, 0, stream>>>(Z2);
  kTf<<<dim3(2048,2), 256, 0, stream>>>(Z2);
  kTinvMul<<<dim3(2048,2,2), 256, 0, stream>>>(Z2, U2, V2, Kr, Ki, scal);
  kHi<<<dim3(1024,2,2), 256, 0, stream>>>(U2, V2);
  kI3C<<<dim3(2048,2), 256, 0, stream>>>(U2, V2, sq);
  kOut<<<dim3(64,4,2), 256, 0, stream>>>(sq, mtxi, out);
}

// Round 4
// 342.140 us; speedup vs baseline: 1.1310x; 1.1310x over previous
//
#include <hip/hip_runtime.h>

#define BLKE 524288      // 128*64*64
#define VOLE 4194304     // 256*128*128
#define TCROP 2097152    // 128*128*128 (t<128 compact complex volume)
#define PI2 6.283185307179586476925286766559

__device__ __forceinline__ float2 cmulf(float2 a, float2 b){
  return make_float2(a.x*b.x - a.y*b.y, a.x*b.y + a.y*b.x);
}
__device__ __forceinline__ float waveSum(float v){
  #pragma unroll
  for (int o=32;o;o>>=1) v += __shfl_xor(v,o);
  return v;
}
__device__ __forceinline__ float waveMaxf(float v){
  #pragma unroll
  for (int o=32;o;o>>=1) v = fmaxf(v,__shfl_xor(v,o));
  return v;
}
__device__ __forceinline__ float waveMinf(float v){
  #pragma unroll
  for (int o=32;o;o>>=1) v = fminf(v,__shfl_xor(v,o));
  return v;
}

// Reduce pA[kappa][256][5] redundantly in every block (identical FP order ->
// identical result in all blocks). Requires blockDim.x == 256.
__device__ __forceinline__ void bcastReduce5(const float* __restrict__ pA, int kap,
    float& sum, float& mnl, float& mxl, float& mnh, float& mxh, float* sm /*>=20*/){
  int tid = threadIdx.x;
  const float* q = pA + kap*1280 + tid*5;
  float s = q[0], a = q[1], b = q[2], c = q[3], d = q[4];
  s = waveSum(s); a = waveMinf(a); b = waveMaxf(b); c = waveMinf(c); d = waveMaxf(d);
  if ((tid&63)==0){ int w = tid>>6; sm[w]=s; sm[4+w]=a; sm[8+w]=b; sm[12+w]=c; sm[16+w]=d; }
  __syncthreads();
  sum = sm[0]+sm[1]+sm[2]+sm[3];
  mnl = fminf(fminf(sm[4],sm[5]),fminf(sm[6],sm[7]));
  mxl = fmaxf(fmaxf(sm[8],sm[9]),fmaxf(sm[10],sm[11]));
  mnh = fminf(fminf(sm[12],sm[13]),fminf(sm[14],sm[15]));
  mxh = fmaxf(fmaxf(sm[16],sm[17]),fmaxf(sm[18],sm[19]));
}

__device__ __forceinline__ float bcastSum256(const float* __restrict__ p, float* sm /*>=4*/){
  int tid = threadIdx.x;
  float s = waveSum(p[tid]);
  if ((tid&63)==0) sm[tid>>6] = s;
  __syncthreads();
  return sm[0]+sm[1]+sm[2]+sm[3];
}

// ---------------- fused conv+mtx operator: M[o][t][s] ----------------
__global__ void kM(const float* __restrict__ mtx, const float* __restrict__ wave,
                   float* __restrict__ M){
  int idx = blockIdx.x*256 + threadIdx.x;   // 32768 = 2*128*128
  int o = idx >> 14, r = idx & 16383;
  int t = r >> 7, s = r & 127;
  float acc = 0.f;
  int mlo = s-31; if (mlo < 0) mlo = 0;
  int mhi = s+31; if (mhi > 127) mhi = 127;
  for (int m = mlo; m <= mhi; m++) acc += mtx[t*128+m]*wave[o*63 + (s-m+31)];
  M[idx] = acc;
}

// ---------------- tmp[o*2+b][t][x] = sum_s M[o][t][s]*feature[b][s][x] ----------------
__global__ void __launch_bounds__(256) kTmp(const float* __restrict__ feat,
                                            const float* __restrict__ M,
                                            float* __restrict__ tmp){
  __shared__ float LF[32][64];
  __shared__ float LM[2][32][33];
  int b = blockIdx.z, tt = blockIdx.y, xt = blockIdx.x;
  int tid = threadIdx.x;
  int xx = tid & 63, tq = tid >> 6;
  float acc0[8] = {}, acc1[8] = {};
  const float* fb = feat + (size_t)b*BLKE;
  for (int sb = 0; sb < 4; sb++){
    #pragma unroll
    for (int j = 0; j < 8; j++){
      int idx = tid + j*256; int s = idx >> 6, x = idx & 63;
      LF[s][x] = fb[(size_t)(sb*32+s)*4096 + xt*64 + x];
    }
    #pragma unroll
    for (int j = 0; j < 8; j++){
      int idx = tid + j*256; int o = idx >> 10, r = idx & 1023;
      int trow = r >> 5, s = r & 31;
      LM[o][trow][s] = M[o*16384 + (tt*32+trow)*128 + sb*32+s];
    }
    __syncthreads();
    for (int s = 0; s < 32; s++){
      float f = LF[s][xx];
      #pragma unroll
      for (int i = 0; i < 8; i++){
        acc0[i] += LM[0][tq*8+i][s]*f;
        acc1[i] += LM[1][tq*8+i][s]*f;
      }
    }
    __syncthreads();
  }
  #pragma unroll
  for (int i = 0; i < 8; i++){
    int t = tt*32 + tq*8 + i;
    tmp[(size_t)(0*2+b)*BLKE + (size_t)t*4096 + xt*64+xx] = acc0[i];
    tmp[(size_t)(1*2+b)*BLKE + (size_t)t*4096 + xt*64+xx] = acc1[i];
  }
}

// ---------------- attention reductions (atomic-free, partials in ws) -------
__global__ void __launch_bounds__(256) kRedA(const float* __restrict__ Kr,
                                             const float* __restrict__ Ki,
                                             float* __restrict__ Lw, float* __restrict__ Hw,
                                             float* __restrict__ pA){
  const float* K = blockIdx.y ? Ki : Kr;
  int kap = blockIdx.y;
  __shared__ float spe[128];
  __shared__ float sm[20];
  int tid = threadIdx.x;
  if (tid < 128) spe[tid] = sinf((float)tid);
  __syncthreads();
  float sum=0.f, mnl=3.4e38f, mxl=-3.4e38f, mnh=3.4e38f, mxh=-3.4e38f;
  int base = blockIdx.x*256 + tid;
  #pragma unroll
  for (int it = 0; it < 8; it++){
    int e = base + it*65536;
    int tau = e >> 12, rem = e & 4095, eta = rem >> 6, om = rem & 63;
    float pe = spe[tau];
    float lo = K[(size_t)((tau+192)&255)*16384 + ((eta+96)&127)*128 + ((om+96)&127)];
    float hi = K[(size_t)(tau+64)*16384 + (eta+32)*128 + (om+32)];
    sum += lo;
    float lp = lo+pe, hp = hi+pe;
    Lw[kap*BLKE + e] = lp;
    Hw[kap*BLKE + e] = hp;
    mnl=fminf(mnl,lp); mxl=fmaxf(mxl,lp);
    mnh=fminf(mnh,hp); mxh=fmaxf(mxh,hp);
  }
  sum = waveSum(sum); mnl=waveMinf(mnl); mxl=waveMaxf(mxl); mnh=waveMinf(mnh); mxh=waveMaxf(mxh);
  if ((tid&63)==0){ int w=tid>>6; sm[w]=sum; sm[4+w]=mnl; sm[8+w]=mxl; sm[12+w]=mnh; sm[16+w]=mxh; }
  __syncthreads();
  if (tid==0){
    float* o = pA + kap*1280 + blockIdx.x*5;
    o[0] = sm[0]+sm[1]+sm[2]+sm[3];
    o[1] = fminf(fminf(sm[4],sm[5]),fminf(sm[6],sm[7]));
    o[2] = fmaxf(fmaxf(sm[8],sm[9]),fmaxf(sm[10],sm[11]));
    o[3] = fminf(fminf(sm[12],sm[13]),fminf(sm[14],sm[15]));
    o[4] = fmaxf(fmaxf(sm[16],sm[17]),fmaxf(sm[18],sm[19]));
  }
}

__global__ void __launch_bounds__(256) kRedB(const float* __restrict__ pA,
                                             const float* __restrict__ Lw,
                                             float* __restrict__ pB,
                                             const float* cw, const float* cb){
  int kap = blockIdx.y;
  __shared__ float sm[20], smo[4];
  float sum,mnl,mxl,mnh,mxh;
  bcastReduce5(pA,kap,sum,mnl,mxl,mnh,mxh,sm);
  float w = cw[0], b = cb[0];
  float s1 = w*(sum*(1.0f/BLKE)) + b;
  float a1 = s1*w, c1 = s1*b;
  float mx = (a1>=0.f) ? a1*mxl+c1 : a1*mnl+c1;
  float acc = 0.f;
  int base = kap*BLKE + blockIdx.x*256 + threadIdx.x;
  #pragma unroll
  for (int it = 0; it < 8; it++){
    float lp = Lw[base + it*65536];
    acc += expf(a1*lp + c1 - mx);
  }
  acc = waveSum(acc);
  if ((threadIdx.x&63)==0) smo[threadIdx.x>>6] = acc;
  __syncthreads();
  if (threadIdx.x==0) pB[kap*256 + blockIdx.x] = smo[0]+smo[1]+smo[2]+smo[3];
}

__global__ void __launch_bounds__(256) kRedC(const float* __restrict__ pA,
                                             const float* __restrict__ pB,
                                             const float* __restrict__ Lw,
                                             float* __restrict__ pC,
                                             const float* cw, const float* cb){
  int kap = blockIdx.y;
  __shared__ float sm[20], smB[4], smo[4];
  float sum,mnl,mxl,mnh,mxh;
  bcastReduce5(pA,kap,sum,mnl,mxl,mnh,mxh,sm);
  float d1 = bcastSum256(pB + kap*256, smB);
  float w = cw[0], b = cb[0];
  float s1 = w*(sum*(1.0f/BLKE)) + b;
  float a1 = s1*w, c1 = s1*b;
  float mx = (a1>=0.f) ? a1*mxl+c1 : a1*mnl+c1;
  float invd = 1.0f/d1;
  float acc = 0.f;
  int base = kap*BLKE + blockIdx.x*256 + threadIdx.x;
  #pragma unroll
  for (int it = 0; it < 8; it++){
    float lp = Lw[base + it*65536];
    float p = expf(a1*lp + c1 - mx)*invd;
    acc += lp/(1.f + expf(-p));
  }
  acc = waveSum(acc);
  if ((threadIdx.x&63)==0) smo[threadIdx.x>>6] = acc;
  __syncthreads();
  if (threadIdx.x==0) pC[kap*256 + blockIdx.x] = smo[0]+smo[1]+smo[2]+smo[3];
}

__global__ void __launch_bounds__(256) kRedD(const float* __restrict__ pA,
                                             const float* __restrict__ pC,
                                             const float* __restrict__ Hw,
                                             float* __restrict__ pD,
                                             const float* cw, const float* cb){
  int kap = blockIdx.y;
  __shared__ float sm[20], smC[4], smo[4];
  float sum,mnl,mxl,mnh,mxh;
  bcastReduce5(pA,kap,sum,mnl,mxl,mnh,mxh,sm);
  float sl2 = bcastSum256(pC + kap*256, smC);
  float w = cw[0], b = cb[0];
  float s2 = w*(sl2*(1.0f/BLKE)) + b;
  float a2 = s2*w, c2 = s2*b;
  float mx = (a2>=0.f) ? a2*mxh+c2 : a2*mnh+c2;
  float acc = 0.f;
  int base = kap*BLKE + blockIdx.x*256 + threadIdx.x;
  #pragma unroll
  for (int it = 0; it < 8; it++){
    float hp = Hw[base + it*65536];
    acc += expf(a2*hp + c2 - mx);
  }
  acc = waveSum(acc);
  if ((threadIdx.x&63)==0) smo[threadIdx.x>>6] = acc;
  __syncthreads();
  if (threadIdx.x==0) pD[kap*256 + blockIdx.x] = smo[0]+smo[1]+smo[2]+smo[3];
}

// finalize: scal[kap*8 + {0..7}] = {a1,c1,mx1,1/d1, a2,c2,mx2,1/d2}
__global__ void __launch_bounds__(256) kFin(const float* __restrict__ pA,
                                            const float* __restrict__ pB,
                                            const float* __restrict__ pC,
                                            const float* __restrict__ pD,
                                            float* __restrict__ scal,
                                            const float* cw, const float* cb){
  __shared__ float sm[20], smB[4], smC[4], smD[4];
  for (int kap = 0; kap < 2; kap++){
    if (kap) __syncthreads();
    float sum,mnl,mxl,mnh,mxh;
    bcastReduce5(pA,kap,sum,mnl,mxl,mnh,mxh,sm);
    float d1  = bcastSum256(pB + kap*256, smB);
    float sl2 = bcastSum256(pC + kap*256, smC);
    float d2  = bcastSum256(pD + kap*256, smD);
    if (threadIdx.x==0){
      float w = cw[0], b = cb[0];
      float s1 = w*(sum*(1.0f/BLKE)) + b;
      float a1 = s1*w, c1 = s1*b;
      float mx1 = (a1>=0.f) ? a1*mxl+c1 : a1*mnl+c1;
      float s2 = w*(sl2*(1.0f/BLKE)) + b;
      float a2 = s2*w, c2 = s2*b;
      float mx2 = (a2>=0.f) ? a2*mxh+c2 : a2*mnh+c2;
      float* Q = scal + kap*8;
      Q[0]=a1; Q[1]=c1; Q[2]=mx1; Q[3]=1.0f/d1;
      Q[4]=a2; Q[5]=c2; Q[6]=mx2; Q[7]=1.0f/d2;
    }
  }
}

// ---------------- W-axis forward FFT, packed load from tmp; grid.y = b ------
__global__ void __launch_bounds__(256) kF1(const float* __restrict__ tmp,
                                           float2* __restrict__ Z2){
  __shared__ float2 bA[4][130], bB[4][130], tw[64];
  int tid = threadIdx.x;
  if (tid < 64){
    double ang = -PI2 * (double)tid / 128.0;
    tw[tid] = make_float2((float)cos(ang), (float)sin(ang));
  }
  int b = blockIdx.y;
  int l = tid >> 6, lane = tid & 63;
  int line = blockIdx.x*4 + l;
  int t = line >> 6, h = line & 63;
  const float* pc = tmp + (size_t)b*BLKE + (size_t)t*4096 + h*64;
  const float* ps = tmp + (size_t)(2+b)*BLKE + (size_t)t*4096 + h*64;
  bA[l][lane] = make_float2(pc[lane], ps[lane]);
  bA[l][lane+64] = make_float2(0.f, 0.f);
  __syncthreads();
  float2 (*src)[130] = bA, (*dst)[130] = bB;
  int m = 1;
  #pragma unroll
  for (int st = 0; st < 7; st++){
    int i = lane;
    int jm = i & ~(m-1);
    float2 a = src[l][i], b2 = src[l][i+64];
    float2 s = make_float2(a.x+b2.x, a.y+b2.y);
    float2 d = make_float2(a.x-b2.x, a.y-b2.y);
    dst[l][i+jm]   = s;
    dst[l][i+jm+m] = cmulf(d, tw[jm]);
    __syncthreads();
    float2 (*tp)[130] = src; src = dst; dst = tp;
    m <<= 1;
  }
  float2* outp = Z2 + (size_t)b*TCROP + (size_t)t*16384 + (size_t)h*128;
  outp[lane]    = src[l][lane];
  outp[lane+64] = src[l][lane+64];
}

// ---------------- H-axis forward (N=128): read h<64, write all; grid.y=b ----
__global__ void __launch_bounds__(256) kHf(float2* __restrict__ Z2){
  __shared__ float2 bA[16][130], bB[16][130], tw[64];
  int tid = threadIdx.x;
  if (tid < 64){
    double ang = -PI2 * (double)tid / 128.0;
    tw[tid] = make_float2((float)cos(ang), (float)sin(ang));
  }
  float2* Z = Z2 + (size_t)blockIdx.y*TCROP;
  int bid = blockIdx.x;                 // 1024 : t<128 x 8 w-groups
  int t = bid >> 3; int w0 = (bid & 7) << 4;
  size_t base = (size_t)t*16384 + w0;
  #pragma unroll
  for (int q = 0; q < 4; q++){
    int idx = q*256 + tid; int wl = idx & 15, hh = idx >> 4;
    bA[wl][hh] = Z[base + (size_t)hh*128 + wl];
    bA[wl][hh+64] = make_float2(0.f, 0.f);
  }
  __syncthreads();
  float2 (*src)[130] = bA, (*dst)[130] = bB;
  int m = 1;
  #pragma unroll
  for (int st = 0; st < 7; st++){
    #pragma unroll
    for (int q = 0; q < 4; q++){
      int g = q*256 + tid; int li = g >> 6; int i = g & 63;
      int jm = i & ~(m-1);
      float2 a = src[li][i], b2 = src[li][i+64];
      float2 s = make_float2(a.x+b2.x, a.y+b2.y);
      float2 d = make_float2(a.x-b2.x, a.y-b2.y);
      dst[li][i+jm]   = s;
      dst[li][i+jm+m] = cmulf(d, tw[jm]);
    }
    __syncthreads();
    float2 (*tp)[130] = src; src = dst; dst = tp;
    m <<= 1;
  }
  #pragma unroll
  for (int q = 0; q < 8; q++){
    int idx = q*256 + tid; int wl = idx & 15, hh = idx >> 4;
    Z[base + (size_t)hh*128 + wl] = src[wl][hh];
  }
}

// ---------------- inline attention-modified multiplier ----------------
__device__ __forceinline__ float attnv(float v, float a, float c, float mx, float invd){
  float p = expf(a*v + c - mx)*invd;
  return v / (1.f + expf(-p));
}
__device__ __forceinline__ float2 wcAt(int t, int h, int w,
                                       const float* __restrict__ Kr, const float* __restrict__ Ki,
                                       const float* spe, const float* P){
  size_t off = (size_t)t*16384 + (size_t)h*128 + w;
  float kr = Kr[off], ki = Ki[off];
  bool center = (t>=64 && t<192) && (h>=32 && h<96) && (w>=32 && w<96);
  int tc = (t+64)&255, hc = (h+32)&127, wc = (w+32)&127;
  bool corner = (tc<128) && (hc<64) && (wc<64);
  float2 o;
  if (center){
    float pe = spe[t-64];
    o.x = attnv(kr+pe, P[4],  P[5],  P[6],  P[7]);
    o.y = attnv(ki+pe, P[12], P[13], P[14], P[15]);
  } else if (corner){
    float pe = spe[tc];
    o.x = attnv(kr+pe, P[0], P[1],  P[2],  P[3]);
    o.y = attnv(ki+pe, P[8], P[9],  P[10], P[11]);
  } else {
    o.x = kr; o.y = ki;
  }
  return o;
}

// ---- fused fwd-T(256) + multiply + 2x inv-T, all in one block -------------
// In-place DIF forward (natural in -> bit-reversed spectrum), spectrum saved
// to registers; multiply U = X*Wc(k) and V' = X*conj(Wc(-k)) (bit-reversed
// index kt = brev8(p)); in-place DIT inverse (bit-reversed in -> natural out).
// Block: 16 w-columns x one h, all 256 t. grid (128*8, b).
__global__ void __launch_bounds__(256) kTfused(const float2* __restrict__ Z2,
                                               float2* __restrict__ U2,
                                               float2* __restrict__ V2,
                                               const float* __restrict__ Kr,
                                               const float* __restrict__ Ki,
                                               const float* __restrict__ scal){
  __shared__ float2 buf[16][258];
  __shared__ float2 tw[128];     // W^k = exp(-2*pi*i*k/256)
  __shared__ float spe[128];
  __shared__ float P[16];
  int tid = threadIdx.x;
  if (tid < 128){
    double ang = -PI2 * (double)tid / 256.0;
    tw[tid] = make_float2((float)cos(ang), (float)sin(ang));
    spe[tid] = sinf((float)tid);
  }
  if (tid < 16) P[tid] = scal[tid];
  int b = blockIdx.y;
  int bid = blockIdx.x;                 // 1024 : 128 h x 8 w-tiles(16)
  int h = bid >> 3, w0 = (bid & 7) << 4;
  int wl = tid & 15, pq = tid >> 4;     // thread owns column wl, rows pq+16q
  const float2* Z = Z2 + (size_t)b*TCROP;
  size_t gbase = (size_t)h*128 + w0 + wl;
  // load t<128 (full 128B lines), zero-pad t>=128
  #pragma unroll
  for (int q = 0; q < 8; q++){
    int p = q*16 + pq;
    buf[wl][p] = Z[(size_t)p*16384 + gbase];
    buf[wl][p+128] = make_float2(0.f, 0.f);
  }
  __syncthreads();
  // ---- DIF forward, 8 stages, in place ----
  for (int st = 0; st < 8; st++){
    int half = 128 >> st;
    #pragma unroll
    for (int q = 0; q < 8; q++){
      int e = q*256 + tid;
      int li = e >> 7, bf = e & 127;
      int j = bf & (half-1);
      int blk = bf >> (7-st);
      int i0 = (blk << (8-st)) + j;
      float2 a = buf[li][i0], c = buf[li][i0+half];
      buf[li][i0] = make_float2(a.x+c.x, a.y+c.y);
      float2 d = make_float2(a.x-c.x, a.y-c.y);
      buf[li][i0+half] = cmulf(d, tw[j << st]);
    }
    __syncthreads();
  }
  // save spectrum (own slots) to registers
  float2 rg[16];
  #pragma unroll
  for (int q = 0; q < 16; q++) rg[q] = buf[wl][q*16 + pq];
  // ---- multiply U = X * Wc(k), k in bit-reversed position ----
  #pragma unroll
  for (int q = 0; q < 16; q++){
    int p = q*16 + pq;
    int kt = __brev((unsigned)p) >> 24;
    float2 wc = wcAt(kt, h, w0 + wl, Kr, Ki, spe, P);
    buf[wl][p] = cmulf(rg[q], wc);
  }
  __syncthreads();
  // ---- DIT inverse (bit-reversed in, natural out), 8 stages ----
  for (int st = 0; st < 8; st++){
    int half = 1 << st;
    #pragma unroll
    for (int q = 0; q < 8; q++){
      int e = q*256 + tid;
      int li = e >> 7, bf = e & 127;
      int j = bf & (half-1);
      int blk = bf >> st;
      int i0 = (blk << (st+1)) + j;
      float2 a = buf[li][i0];
      float2 cc = buf[li][i0+half];
      float2 w = tw[j << (7-st)];
      float2 c = cmulf(cc, make_float2(w.x, -w.y));
      buf[li][i0] = make_float2(a.x+c.x, a.y+c.y);
      buf[li][i0+half] = make_float2(a.x-c.x, a.y-c.y);
    }
    __syncthreads();
  }
  // write U (t<128 crop), own slots
  float2* Uo = U2 + (size_t)b*TCROP;
  #pragma unroll
  for (int q = 0; q < 8; q++){
    int p = q*16 + pq;
    Uo[(size_t)p*16384 + gbase] = buf[wl][p];
  }
  // ---- multiply V' = X * conj(Wc(-k)) (own slots; safe w/o barrier) ----
  #pragma unroll
  for (int q = 0; q < 16; q++){
    int p = q*16 + pq;
    int kt = __brev((unsigned)p) >> 24;
    int tm = (256-kt)&255, hm = (128-h)&127, wm = (128-(w0+wl))&127;
    float2 wc = wcAt(tm, hm, wm, Kr, Ki, spe, P);
    wc.y = -wc.y;
    buf[wl][p] = cmulf(rg[q], wc);
  }
  __syncthreads();
  // ---- DIT inverse again ----
  for (int st = 0; st < 8; st++){
    int half = 1 << st;
    #pragma unroll
    for (int q = 0; q < 8; q++){
      int e = q*256 + tid;
      int li = e >> 7, bf = e & 127;
      int j = bf & (half-1);
      int blk = bf >> st;
      int i0 = (blk << (st+1)) + j;
      float2 a = buf[li][i0];
      float2 cc = buf[li][i0+half];
      float2 w = tw[j << (7-st)];
      float2 c = cmulf(cc, make_float2(w.x, -w.y));
      buf[li][i0] = make_float2(a.x+c.x, a.y+c.y);
      buf[li][i0+half] = make_float2(a.x-c.x, a.y-c.y);
    }
    __syncthreads();
  }
  float2* Vo = V2 + (size_t)b*TCROP;
  #pragma unroll
  for (int q = 0; q < 8; q++){
    int p = q*16 + pq;
    Vo[(size_t)p*16384 + gbase] = buf[wl][p];
  }
}

// ---------------- H-axis inverse (N=128) on compact buffers: grid (1024,b,uv)
__global__ void __launch_bounds__(256) kHi(float2* __restrict__ U2, float2* __restrict__ V2){
  __shared__ float2 bA[16][130], bB[16][130], tw[64];
  int tid = threadIdx.x;
  if (tid < 64){
    double ang = PI2 * (double)tid / 128.0;
    tw[tid] = make_float2((float)cos(ang), (float)sin(ang));
  }
  float2* Z = (blockIdx.z ? V2 : U2) + (size_t)blockIdx.y*TCROP;
  int bid = blockIdx.x;                 // 1024 : t<128 x 8 w-groups
  int t = bid >> 3; int w0 = (bid & 7) << 4;
  size_t base = (size_t)t*16384 + w0;
  #pragma unroll
  for (int q = 0; q < 8; q++){
    int idx = q*256 + tid; int wl = idx & 15, hh = idx >> 4;
    bA[wl][hh] = Z[base + (size_t)hh*128 + wl];
  }
  __syncthreads();
  float2 (*src)[130] = bA, (*dst)[130] = bB;
  int m = 1;
  #pragma unroll
  for (int st = 0; st < 7; st++){
    #pragma unroll
    for (int q = 0; q < 4; q++){
      int g = q*256 + tid; int li = g >> 6; int i = g & 63;
      int jm = i & ~(m-1);
      float2 a = src[li][i], b2 = src[li][i+64];
      float2 s = make_float2(a.x+b2.x, a.y+b2.y);
      float2 d = make_float2(a.x-b2.x, a.y-b2.y);
      dst[li][i+jm]   = s;
      dst[li][i+jm+m] = cmulf(d, tw[jm]);
    }
    __syncthreads();
    float2 (*tp)[130] = src; src = dst; dst = tp;
    m <<= 1;
  }
  #pragma unroll
  for (int q = 0; q < 4; q++){
    int idx = q*256 + tid; int wl = idx & 15, hh = idx >> 4;   // hh < 64
    Z[base + (size_t)hh*128 + wl] = src[wl][hh];
  }
}

// -- fused W-axis inverse + combine: per line FFT U then V; s=y*conj(v)*sc^2 --
__global__ void __launch_bounds__(256) kI3C(const float2* __restrict__ U2,
                                            const float2* __restrict__ V2,
                                            float* __restrict__ sq){
  __shared__ float2 bA[4][130], bB[4][130], tw[64];
  int tid = threadIdx.x;
  if (tid < 64){
    double ang = PI2 * (double)tid / 128.0;
    tw[tid] = make_float2((float)cos(ang), (float)sin(ang));
  }
  int b = blockIdx.y;
  int l = tid >> 6, lane = tid & 63;
  int line = blockIdx.x*4 + l;         // t<128, h<64
  int t = line >> 6, h = line & 63;
  size_t off = (size_t)b*TCROP + (size_t)t*16384 + (size_t)h*128;
  // ---- U line ----
  bA[l][lane]    = U2[off + lane];
  bA[l][lane+64] = U2[off + lane + 64];
  __syncthreads();
  float2 (*src)[130] = bA, (*dst)[130] = bB;
  int m = 1;
  #pragma unroll
  for (int st = 0; st < 7; st++){
    int i = lane;
    int jm = i & ~(m-1);
    float2 a = src[l][i], b2 = src[l][i+64];
    float2 s = make_float2(a.x+b2.x, a.y+b2.y);
    float2 d = make_float2(a.x-b2.x, a.y-b2.y);
    dst[l][i+jm]   = s;
    dst[l][i+jm+m] = cmulf(d, tw[jm]);
    __syncthreads();
    float2 (*tp)[130] = src; src = dst; dst = tp;
    m <<= 1;
  }
  float2 y = src[l][lane];
  // ---- V line (dst != src holds y's buffer; loads go to dst side) ----
  dst[l][lane]    = V2[off + lane];
  dst[l][lane+64] = V2[off + lane + 64];
  __syncthreads();
  src = dst; dst = (src == bA) ? bB : bA;
  m = 1;
  #pragma unroll
  for (int st = 0; st < 7; st++){
    int i = lane;
    int jm = i & ~(m-1);
    float2 a = src[l][i], b2 = src[l][i+64];
    float2 s = make_float2(a.x+b2.x, a.y+b2.y);
    float2 d = make_float2(a.x-b2.x, a.y-b2.y);
    dst[l][i+jm]   = s;
    dst[l][i+jm+m] = cmulf(d, tw[jm]);
    __syncthreads();
    float2 (*tp)[130] = src; src = dst; dst = tp;
    m <<= 1;
  }
  float2 v = src[l][lane];
  // s = y * conj(v) * sc^2  (y' = conj(ifft(Z*conj(Wc(-.)))))
  const float sc = 1.0f/(float)VOLE;
  const float sc2 = sc*sc;
  float2 s = cmulf(y, make_float2(v.x, -v.y));
  s.x *= sc2; s.y *= sc2;
  float mag = 0.5f*(sqrtf(s.x*s.x + s.y*s.y) + s.x);
  mag = fmaxf(mag, 0.f);
  sq[(size_t)b*BLKE + (size_t)t*4096 + h*64 + lane] = sqrtf(mag);
}

// ---------------- out[b][t][x] = sum_m mtxi[t][m]*sq[b][m][x] ----------------
__global__ void __launch_bounds__(256) kOut(const float* __restrict__ sq,
                                            const float* __restrict__ mtxi,
                                            float* __restrict__ out){
  __shared__ float LF[32][64];
  __shared__ float LM[32][33];
  int b = blockIdx.z, tt = blockIdx.y, xt = blockIdx.x;
  int tid = threadIdx.x;
  int xx = tid & 63, tq = tid >> 6;
  float acc[8] = {};
  const float* fb = sq + (size_t)b*BLKE;
  for (int sb = 0; sb < 4; sb++){
    #pragma unroll
    for (int j = 0; j < 8; j++){
      int idx = tid + j*256; int s = idx >> 6, x = idx & 63;
      LF[s][x] = fb[(size_t)(sb*32+s)*4096 + xt*64 + x];
    }
    #pragma unroll
    for (int j = 0; j < 4; j++){
      int idx = tid + j*256; int trow = idx >> 5, s = idx & 31;
      LM[trow][s] = mtxi[(tt*32+trow)*128 + sb*32+s];
    }
    __syncthreads();
    for (int s = 0; s < 32; s++){
      float f = LF[s][xx];
      #pragma unroll
      for (int i = 0; i < 8; i++) acc[i] += LM[tq*8+i][s]*f;
    }
    __syncthreads();
  }
  #pragma unroll
  for (int i = 0; i < 8; i++){
    int t = tt*32 + tq*8 + i;
    out[(size_t)b*BLKE + (size_t)t*4096 + xt*64+xx] = acc[i];
  }
}

extern "C" void kernel_launch(void* const* d_in, const int* in_sizes, int n_in,
                              void* d_out, int out_size, void* d_ws, size_t ws_size,
                              hipStream_t stream){
  const float* feature = (const float*)d_in[0];
  const float* convW   = (const float*)d_in[1];
  const float* convB   = (const float*)d_in[2];
  const float* wave    = (const float*)d_in[3];
  const float* Kr      = (const float*)d_in[4];
  const float* Ki      = (const float*)d_in[5];
  const float* mtx     = (const float*)d_in[6];
  const float* mtxi    = (const float*)d_in[7];
  float* out = (float*)d_out;
  float* ws  = (float*)d_ws;

  float*  M    = ws;                         // 32768
  float*  scal = ws + 32768;                 // 16
  float*  pA   = ws + 32832;                 // 2560
  float*  pB   = ws + 35392;                 // 512
  float*  pC   = ws + 35904;                 // 512
  float*  pD   = ws + 36416;                 // 512
  float*  tmp  = ws + 65536;                 // 2097152
  float*  sq   = ws + 65536 + 2097152;       // 1048576
  float2* Z2   = (float2*)(ws + 3211264);    // 2 * TCROP float2 (33.5 MB)
  float2* U2   = (float2*)(ws + 11599872);   // 2 * TCROP float2
  float2* V2   = (float2*)(ws + 19988480);   // 2 * TCROP float2
  // Lw/Hw alias U2 (consumed by kRedB/C/D before kTfused writes U2)
  float*  Lw   = (float*)U2;                 // 2*BLKE
  float*  Hw   = ((float*)U2) + 1048576;     // 2*BLKE

  kM<<<128, 256, 0, stream>>>(mtx, wave, M);
  kTmp<<<dim3(64,4,2), 256, 0, stream>>>(feature, M, tmp);
  kRedA<<<dim3(256,2), 256, 0, stream>>>(Kr, Ki, Lw, Hw, pA);
  kRedB<<<dim3(256,2), 256, 0, stream>>>(pA, Lw, pB, convW, convB);
  kRedC<<<dim3(256,2), 256, 0, stream>>>(pA, pB, Lw, pC, convW, convB);
  kRedD<<<dim3(256,2), 256, 0, stream>>>(pA, pC, Hw, pD, convW, convB);
  kFin<<<1, 256, 0, stream>>>(pA, pB, pC, pD, scal, convW, convB);

  kF1<<<dim3(2048,2), 256, 0, stream>>>(tmp, Z2);
  kHf<<<dim3(1024,2), 256, 0, stream>>>(Z2);
  kTfused<<<dim3(1024,2), 256, 0, stream>>>(Z2, U2, V2, Kr, Ki, scal);
  kHi<<<dim3(1024,2,2), 256, 0, stream>>>(U2, V2);
  kI3C<<<dim3(2048,2), 256, 0, stream>>>(U2, V2, sq);
  kOut<<<dim3(64,4,2), 256, 0, stream>>>(sq, mtxi, out);
}